// Round 3
// baseline (1418.416 us; speedup 1.0000x reference)
//
#include <hip/hip_runtime.h>

#define N_TOK 2048
#define DMODEL 1024
#define NHEAD 16
#define HDIM 64

typedef __attribute__((ext_vector_type(8))) __bf16 bf16x8;
typedef __attribute__((ext_vector_type(4))) float f32x4;

__device__ __forceinline__ float bf2f(unsigned short h) {
  return __uint_as_float(((unsigned int)h) << 16);
}
__device__ __forceinline__ unsigned short f2bf(float f) {
  unsigned int u = __float_as_uint(f);
  unsigned int r = (u + 0x7fffu + ((u >> 16) & 1u)) >> 16;
  return (unsigned short)r;
}
// pack 4 floats -> 4 fp8 e4m3 (OCP on gfx950) bytes, little-endian order a,b,c,d
__device__ __forceinline__ unsigned int pack4_fp8(float a, float b, float c, float d) {
  int v = __builtin_amdgcn_cvt_pk_fp8_f32(a, b, 0, false);
  v = __builtin_amdgcn_cvt_pk_fp8_f32(c, d, v, true);
  return (unsigned int)v;
}

__device__ __forceinline__ void async16(const void* g, void* l) {
  __builtin_amdgcn_global_load_lds((__attribute__((address_space(1))) void*)(g),
                                   (__attribute__((address_space(3))) void*)(l),
                                   16, 0, 0);
}

#define FP8_SCALE 256.0f
#define FP8_INV2  (1.0f / (256.0f * 256.0f))

// ---------------- bf16 GEMM: C = alpha*(A @ B^T) [+bias[col]] [+beta*Eb(bf16)] ----------------
struct GemmP {
  const unsigned short* A;
  const unsigned short* B;
  const unsigned short* Eb;
  const float* bias;
  float* Cf;
  unsigned short* Cb;
  long long sA, sB, sE, sCf, sCb;
  int lda, ldb, ldE, ldCf, ldCb;
  int M, N, K;
  float alpha, beta;
};

__global__ __launch_bounds__(256) void gemm_bt_kernel(GemmP g) {
  __shared__ __attribute__((aligned(16))) unsigned short As[128 * 32];
  __shared__ __attribute__((aligned(16))) unsigned short Bs[128 * 32];
  const int tid = threadIdx.x;
  const int lane = tid & 63;
  const int wv = tid >> 6;
  const int wr = wv >> 1, wc = wv & 1;
  const long long z = blockIdx.z;
  const unsigned short* A = g.A + z * g.sA;
  const unsigned short* B = g.B + z * g.sB;
  const int tm = blockIdx.y * 128;
  const int tn = blockIdx.x * 128;

  const int r0 = tid >> 2;
  const int r1 = (tid + 256) >> 2;
  const int kof = (tid & 3) * 8;
  int bn0 = tn + r0; if (bn0 > g.N - 1) bn0 = g.N - 1;
  int bn1 = tn + r1; if (bn1 > g.N - 1) bn1 = g.N - 1;

  const unsigned short* pa0 = A + (long long)(tm + r0) * g.lda + kof;
  const unsigned short* pa1 = A + (long long)(tm + r1) * g.lda + kof;
  const unsigned short* pb0 = B + (long long)bn0 * g.ldb + kof;
  const unsigned short* pb1 = B + (long long)bn1 * g.ldb + kof;

  unsigned short* la0 = &As[tid * 8];
  unsigned short* la1 = &As[(tid + 256) * 8];
  unsigned short* lb0 = &Bs[tid * 8];
  unsigned short* lb1 = &Bs[(tid + 256) * 8];

  const int aroff = (wr * 64 + (lane & 15)) * 32 + (lane >> 4) * 8;
  const int broff = (wc * 64 + (lane & 15)) * 32 + (lane >> 4) * 8;

  f32x4 acc[4][4] = {};

  for (int kk = 0; kk < g.K; kk += 32) {
    __syncthreads();
    async16(pa0 + kk, la0);
    async16(pa1 + kk, la1);
    async16(pb0 + kk, lb0);
    async16(pb1 + kk, lb1);
    __syncthreads();
    bf16x8 af[4], bfr[4];
#pragma unroll
    for (int i = 0; i < 4; i++)
      af[i] = *(const bf16x8*)&As[aroff + i * 16 * 32];
#pragma unroll
    for (int j = 0; j < 4; j++)
      bfr[j] = *(const bf16x8*)&Bs[broff + j * 16 * 32];
#pragma unroll
    for (int i = 0; i < 4; i++)
#pragma unroll
      for (int j = 0; j < 4; j++)
        acc[i][j] = __builtin_amdgcn_mfma_f32_16x16x32_bf16(af[i], bfr[j], acc[i][j], 0, 0, 0);
  }

  const unsigned short* Eb = g.Eb ? g.Eb + z * g.sE : nullptr;
  float* Cf = g.Cf ? g.Cf + z * g.sCf : nullptr;
  unsigned short* Cb = g.Cb ? g.Cb + z * g.sCb : nullptr;
  const int cbase = tn + wc * 64 + (lane & 15);
  const int rbase = tm + wr * 64 + (lane >> 4) * 4;
#pragma unroll
  for (int i = 0; i < 4; i++) {
#pragma unroll
    for (int j = 0; j < 4; j++) {
      int col = cbase + j * 16;
      if (col < g.N) {
        float bs = g.bias ? g.bias[col] : 0.f;
#pragma unroll
        for (int r = 0; r < 4; r++) {
          int row = rbase + i * 16 + r;
          float v = g.alpha * acc[i][j][r] + bs;
          if (Eb) v += g.beta * bf2f(Eb[(long long)row * g.ldE + col]);
          if (Cf) Cf[(long long)row * g.ldCf + col] = v;
          if (Cb) Cb[(long long)row * g.ldCb + col] = f2bf(v);
        }
      }
    }
  }
}

// ---------------- fp8 GEMM (diffusion): C = alpha*(A @ B^T) + beta*Eb ----------------
// A: [M,K] fp8 row-major, B: [N,K] fp8 row-major. K%64==0, M,N%128==0. BK=64.
struct Gemm8P {
  const unsigned char* A;
  const unsigned char* B;
  const unsigned short* Eb;
  float* Cf;
  unsigned short* Cb;
  long long sA, sB, sE, sCf, sCb;
  int lda, ldb, ldE, ldCf, ldCb;
  int K;
  float alpha, beta;
};

__global__ __launch_bounds__(256) void gemm_fp8_kernel(Gemm8P g) {
  __shared__ __attribute__((aligned(16))) unsigned char As[128 * 64];
  __shared__ __attribute__((aligned(16))) unsigned char Bs[128 * 64];
  const int tid = threadIdx.x;
  const int lane = tid & 63;
  const int wv = tid >> 6;
  const int wr = wv >> 1, wc = wv & 1;
  const long long z = blockIdx.z;
  const unsigned char* A = g.A + z * g.sA;
  const unsigned char* B = g.B + z * g.sB;
  const int tm = blockIdx.y * 128;
  const int tn = blockIdx.x * 128;

  // staging: chunk c (0..511) covers row c>>2, k-byte (c&3)*16; thread does c=tid and c=tid+256
  const int r0 = tid >> 2;
  const int r1 = 64 + (tid >> 2);
  const int kof = (tid & 3) * 16;
  const unsigned char* pa0 = A + (long long)(tm + r0) * g.lda + kof;
  const unsigned char* pa1 = A + (long long)(tm + r1) * g.lda + kof;
  const unsigned char* pb0 = B + (long long)(tn + r0) * g.ldb + kof;
  const unsigned char* pb1 = B + (long long)(tn + r1) * g.ldb + kof;
  unsigned char* la0 = &As[tid * 16];
  unsigned char* la1 = &As[(tid + 256) * 16];
  unsigned char* lb0 = &Bs[tid * 16];
  unsigned char* lb1 = &Bs[(tid + 256) * 16];

  const int aroff = (wr * 64 + (lane & 15)) * 64 + (lane >> 4) * 8;
  const int broff = (wc * 64 + (lane & 15)) * 64 + (lane >> 4) * 8;

  f32x4 acc[4][4] = {};

  for (int kk = 0; kk < g.K; kk += 64) {
    __syncthreads();
    async16(pa0 + kk, la0);
    async16(pa1 + kk, la1);
    async16(pb0 + kk, lb0);
    async16(pb1 + kk, lb1);
    __syncthreads();
#pragma unroll
    for (int ks = 0; ks < 2; ks++) {
      long af[4], bf[4];
#pragma unroll
      for (int i = 0; i < 4; i++)
        af[i] = *(const long*)&As[aroff + ks * 32 + i * 16 * 64];
#pragma unroll
      for (int j = 0; j < 4; j++)
        bf[j] = *(const long*)&Bs[broff + ks * 32 + j * 16 * 64];
#pragma unroll
      for (int i = 0; i < 4; i++)
#pragma unroll
        for (int j = 0; j < 4; j++)
          acc[i][j] = __builtin_amdgcn_mfma_f32_16x16x32_fp8_fp8(af[i], bf[j], acc[i][j], 0, 0, 0);
    }
  }

  const unsigned short* Eb = g.Eb + z * g.sE;
  float* Cf = g.Cf + z * g.sCf;
  unsigned short* Cb = g.Cb + z * g.sCb;
  const int cbase = tn + wc * 64 + (lane & 15);
  const int rbase = tm + wr * 64 + (lane >> 4) * 4;
#pragma unroll
  for (int i = 0; i < 4; i++) {
#pragma unroll
    for (int j = 0; j < 4; j++) {
      int col = cbase + j * 16;
#pragma unroll
      for (int r = 0; r < 4; r++) {
        int row = rbase + i * 16 + r;
        float v = g.alpha * acc[i][j][r] + g.beta * bf2f(Eb[(long long)row * g.ldE + col]);
        Cf[(long long)row * g.ldCf + col] = v;
        Cb[(long long)row * g.ldCb + col] = f2bf(v);
      }
    }
  }
}

// ---------------- attn partial: Part = p(128-row tile) @ V (64 cols), K-split ----------------
struct AttnP {
  const unsigned short* A;  // p bf16 [N_TOK, N_TOK] per head
  const unsigned short* B;  // V^T bf16 [64, N_TOK] per head
  float* Part;              // [4][G][N_TOK][64]
  long long sA, sB;
  int lda, ldb, G;
};

__global__ __launch_bounds__(256) void attn_part_kernel(AttnP g) {
  __shared__ __attribute__((aligned(16))) unsigned short As[128 * 32];
  __shared__ __attribute__((aligned(16))) unsigned short Bs[64 * 32];
  const int tid = threadIdx.x;
  const int lane = tid & 63;
  const int w = tid >> 6;
  const int z = blockIdx.y;
  const int kz = blockIdx.z;
  const unsigned short* A = g.A + (long long)z * g.sA;
  const unsigned short* B = g.B + (long long)z * g.sB;
  const int tm = blockIdx.x * 128;
  const int k0 = kz * 512;

  const int rA0 = tid >> 2;
  const int rA1 = 64 + (tid >> 2);
  const int kof = (tid & 3) * 8;
  const unsigned short* pa0 = A + (long long)(tm + rA0) * g.lda + k0 + kof;
  const unsigned short* pa1 = A + (long long)(tm + rA1) * g.lda + k0 + kof;
  const unsigned short* pb0 = B + (long long)(tid >> 2) * g.ldb + k0 + kof;
  unsigned short* la0 = &As[tid * 8];
  unsigned short* la1 = &As[(tid + 256) * 8];
  unsigned short* lb0 = &Bs[tid * 8];

  const int aoff = (w * 32 + (lane & 15)) * 32 + (lane >> 4) * 8;
  const int boff = (lane & 15) * 32 + (lane >> 4) * 8;

  f32x4 acc[2][4] = {};

  for (int kk = 0; kk < 512; kk += 32) {
    __syncthreads();
    async16(pa0 + kk, la0);
    async16(pa1 + kk, la1);
    async16(pb0 + kk, lb0);
    __syncthreads();
    bf16x8 af[2], bfr[4];
#pragma unroll
    for (int i = 0; i < 2; i++)
      af[i] = *(const bf16x8*)&As[aoff + i * 16 * 32];
#pragma unroll
    for (int j = 0; j < 4; j++)
      bfr[j] = *(const bf16x8*)&Bs[boff + j * 16 * 32];
#pragma unroll
    for (int i = 0; i < 2; i++)
#pragma unroll
      for (int j = 0; j < 4; j++)
        acc[i][j] = __builtin_amdgcn_mfma_f32_16x16x32_bf16(af[i], bfr[j], acc[i][j], 0, 0, 0);
  }

  float* P = g.Part + ((long long)(kz * g.G + z) * N_TOK + tm) * 64;
#pragma unroll
  for (int i = 0; i < 2; i++) {
#pragma unroll
    for (int j = 0; j < 4; j++) {
      int col = (lane & 15) + j * 16;
#pragma unroll
      for (int r = 0; r < 4; r++) {
        int row = w * 32 + i * 16 + (lane >> 4) * 4 + r;
        P[(long long)row * 64 + col] = acc[i][j][r];
      }
    }
  }
}

// ATT[row][ (h0+z)*64 + col ] = bf16( sum_kz Part )
__global__ __launch_bounds__(256) void attn_reduce_kernel(const float* Part, unsigned short* ATT,
                                                          int G, int h0) {
  int idx = blockIdx.x * 256 + threadIdx.x;  // 4 floats each
  int f = idx * 4;
  int z = f / (N_TOK * 64);
  int rem = f % (N_TOK * 64);
  int row = rem >> 6;
  int col = rem & 63;
  long long stride = (long long)G * N_TOK * 64;
  const float* p0 = Part + ((long long)z * N_TOK + row) * 64 + col;
  float4 s = *(const float4*)p0;
  float4 a = *(const float4*)(p0 + stride);
  float4 b = *(const float4*)(p0 + 2 * stride);
  float4 c = *(const float4*)(p0 + 3 * stride);
  s.x += a.x + b.x + c.x; s.y += a.y + b.y + c.y;
  s.z += a.z + b.z + c.z; s.w += a.w + b.w + c.w;
  uint2 o;
  o.x = (unsigned)f2bf(s.x) | ((unsigned)f2bf(s.y) << 16);
  o.y = (unsigned)f2bf(s.z) | ((unsigned)f2bf(s.w) << 16);
  *(uint2*)&ATT[(long long)row * DMODEL + (h0 + z) * 64 + col] = o;
}

// ---------------- elementwise / transpose / softmax helpers ----------------

__global__ __launch_bounds__(256) void cast_f32_bf16_kernel(const float* x, unsigned short* y) {
  int i = blockIdx.x * 256 + threadIdx.x;
  const float4* src = (const float4*)x;
  float4 a = src[i * 2], b = src[i * 2 + 1];
  uint4 o;
  o.x = (unsigned)f2bf(a.x) | ((unsigned)f2bf(a.y) << 16);
  o.y = (unsigned)f2bf(a.z) | ((unsigned)f2bf(a.w) << 16);
  o.z = (unsigned)f2bf(b.x) | ((unsigned)f2bf(b.y) << 16);
  o.w = (unsigned)f2bf(b.z) | ((unsigned)f2bf(b.w) << 16);
  ((uint4*)y)[i] = o;
}

__global__ __launch_bounds__(256) void transpose_w_kernel(const float* in, unsigned short* out,
                                                          int rows, int cols) {
  __shared__ float t[32][33];
  int c = blockIdx.x * 32 + threadIdx.x;
  int r0 = blockIdx.y * 32;
#pragma unroll
  for (int j = 0; j < 32; j += 8)
    t[threadIdx.y + j][threadIdx.x] = in[(long long)(r0 + threadIdx.y + j) * cols + c];
  __syncthreads();
  int r = r0 + threadIdx.x;
#pragma unroll
  for (int j = 0; j < 32; j += 8)
    out[(long long)(blockIdx.x * 32 + threadIdx.y + j) * rows + r] =
        f2bf(t[threadIdx.x][threadIdx.y + j]);
}

__global__ __launch_bounds__(256) void transpose_bf_kernel(const unsigned short* in,
                                                           unsigned short* out,
                                                           int rows, int cols) {
  __shared__ unsigned short t[32][34];
  int c = blockIdx.x * 32 + threadIdx.x;
  int r0 = blockIdx.y * 32;
#pragma unroll
  for (int j = 0; j < 32; j += 8)
    t[threadIdx.y + j][threadIdx.x] = in[(long long)(r0 + threadIdx.y + j) * cols + c];
  __syncthreads();
  int r = r0 + threadIdx.x;
#pragma unroll
  for (int j = 0; j < 32; j += 8)
    out[(long long)(blockIdx.x * 32 + threadIdx.y + j) * rows + r] = t[threadIdx.x][threadIdx.y + j];
}

// softmax over fp32 rows -> bf16 P0 and fp8 P0q (scaled by FP8_SCALE)
__global__ __launch_bounds__(256) void softmax_rows_kernel(const float* S, unsigned short* P,
                                                           unsigned char* P8, float scale) {
  __shared__ float redm[4];
  __shared__ float reds[4];
  long long row = blockIdx.x;
  const float4* src = (const float4*)(S + row * 2048);
  float4 A = src[threadIdx.x * 2], B = src[threadIdx.x * 2 + 1];
  float v[8] = {A.x, A.y, A.z, A.w, B.x, B.y, B.z, B.w};
#pragma unroll
  for (int i = 0; i < 8; i++) v[i] *= scale;
  float m = v[0];
#pragma unroll
  for (int i = 1; i < 8; i++) m = fmaxf(m, v[i]);
#pragma unroll
  for (int o = 32; o > 0; o >>= 1) m = fmaxf(m, __shfl_xor(m, o));
  if ((threadIdx.x & 63) == 0) redm[threadIdx.x >> 6] = m;
  __syncthreads();
  m = fmaxf(fmaxf(redm[0], redm[1]), fmaxf(redm[2], redm[3]));
  float e[8];
  float s = 0.f;
#pragma unroll
  for (int i = 0; i < 8; i++) { e[i] = __expf(v[i] - m); s += e[i]; }
#pragma unroll
  for (int o = 32; o > 0; o >>= 1) s += __shfl_xor(s, o);
  if ((threadIdx.x & 63) == 0) reds[threadIdx.x >> 6] = s;
  __syncthreads();
  s = (reds[0] + reds[1]) + (reds[2] + reds[3]);
  float inv = 1.f / s;
  float p[8];
#pragma unroll
  for (int i = 0; i < 8; i++) p[i] = e[i] * inv;
  uint4 o4;
  o4.x = (unsigned)f2bf(p[0]) | ((unsigned)f2bf(p[1]) << 16);
  o4.y = (unsigned)f2bf(p[2]) | ((unsigned)f2bf(p[3]) << 16);
  o4.z = (unsigned)f2bf(p[4]) | ((unsigned)f2bf(p[5]) << 16);
  o4.w = (unsigned)f2bf(p[6]) | ((unsigned)f2bf(p[7]) << 16);
  ((uint4*)(P + row * 2048))[threadIdx.x] = o4;
  uint2 q;
  q.x = pack4_fp8(p[0] * FP8_SCALE, p[1] * FP8_SCALE, p[2] * FP8_SCALE, p[3] * FP8_SCALE);
  q.y = pack4_fp8(p[4] * FP8_SCALE, p[5] * FP8_SCALE, p[6] * FP8_SCALE, p[7] * FP8_SCALE);
  *(uint2*)(P8 + row * 2048 + threadIdx.x * 8) = q;
}

// per-row max and 1/sumexp from bf16 sim
__global__ __launch_bounds__(256) void rowstats_bf_kernel(const unsigned short* S, float* mx,
                                                          float* rz, float scale) {
  __shared__ float redm[4];
  __shared__ float reds[4];
  long long row = blockIdx.x;
  uint4 raw = ((const uint4*)(S + row * 2048))[threadIdx.x];
  unsigned int w[4] = {raw.x, raw.y, raw.z, raw.w};
  float v[8];
#pragma unroll
  for (int i = 0; i < 4; i++) {
    v[2 * i] = bf2f((unsigned short)(w[i] & 0xffff)) * scale;
    v[2 * i + 1] = bf2f((unsigned short)(w[i] >> 16)) * scale;
  }
  float m = v[0];
#pragma unroll
  for (int i = 1; i < 8; i++) m = fmaxf(m, v[i]);
#pragma unroll
  for (int o = 32; o > 0; o >>= 1) m = fmaxf(m, __shfl_xor(m, o));
  if ((threadIdx.x & 63) == 0) redm[threadIdx.x >> 6] = m;
  __syncthreads();
  m = fmaxf(fmaxf(redm[0], redm[1]), fmaxf(redm[2], redm[3]));
  float s = 0.f;
#pragma unroll
  for (int i = 0; i < 8; i++) s += __expf(v[i] - m);
#pragma unroll
  for (int o = 32; o > 0; o >>= 1) s += __shfl_xor(s, o);
  if ((threadIdx.x & 63) == 0) reds[threadIdx.x >> 6] = s;
  __syncthreads();
  if (threadIdx.x == 0) {
    s = (reds[0] + reds[1]) + (reds[2] + reds[3]);
    mx[row] = m;
    rz[row] = 1.f / s;
  }
}

// PT(fp8, xFP8_SCALE)[z][m][n] = exp(scale*S[z][m][n] - mx[n]) * rz[n]  (sim symmetric)
__global__ __launch_bounds__(256) void build_pt_kernel(const unsigned short* S, const float* mx,
                                                       const float* rz, unsigned char* PT,
                                                       float scale) {
  long long z = blockIdx.y;
  long long m = blockIdx.x;
  uint4 raw = ((const uint4*)(S + (z * 2048 + m) * 2048))[threadIdx.x];
  unsigned int w[4] = {raw.x, raw.y, raw.z, raw.w};
  float v[8];
#pragma unroll
  for (int i = 0; i < 4; i++) {
    v[2 * i] = bf2f((unsigned short)(w[i] & 0xffff)) * scale;
    v[2 * i + 1] = bf2f((unsigned short)(w[i] >> 16)) * scale;
  }
  const float4* mx4 = (const float4*)(mx + z * 2048);
  const float4* rz4 = (const float4*)(rz + z * 2048);
  float4 ma = mx4[threadIdx.x * 2], mb = mx4[threadIdx.x * 2 + 1];
  float4 ra = rz4[threadIdx.x * 2], rb = rz4[threadIdx.x * 2 + 1];
  float p[8];
  p[0] = __expf(v[0] - ma.x) * ra.x * FP8_SCALE;
  p[1] = __expf(v[1] - ma.y) * ra.y * FP8_SCALE;
  p[2] = __expf(v[2] - ma.z) * ra.z * FP8_SCALE;
  p[3] = __expf(v[3] - ma.w) * ra.w * FP8_SCALE;
  p[4] = __expf(v[4] - mb.x) * rb.x * FP8_SCALE;
  p[5] = __expf(v[5] - mb.y) * rb.y * FP8_SCALE;
  p[6] = __expf(v[6] - mb.z) * rb.z * FP8_SCALE;
  p[7] = __expf(v[7] - mb.w) * rb.w * FP8_SCALE;
  uint2 q;
  q.x = pack4_fp8(p[0], p[1], p[2], p[3]);
  q.y = pack4_fp8(p[4], p[5], p[6], p[7]);
  *(uint2*)(PT + (z * 2048 + m) * 2048 + threadIdx.x * 8) = q;
}

// ---------------- driver ----------------

extern "C" void kernel_launch(void* const* d_in, const int* in_sizes, int n_in,
                              void* d_out, int out_size, void* d_ws, size_t ws_size,
                              hipStream_t stream) {
  const float* hs = (const float*)d_in[0];
  const float* Wq = (const float*)d_in[1];
  const float* bq = (const float*)d_in[2];
  const float* Wk = (const float*)d_in[3];
  const float* bk = (const float*)d_in[4];
  const float* Wv = (const float*)d_in[5];
  const float* bv = (const float*)d_in[6];
  const float* Wo = (const float*)d_in[7];
  const float* bo = (const float*)d_in[8];
  float* out = (float*)d_out;
  float* outp = out + (size_t)N_TOK * DMODEL;

  char* base = (char*)d_ws;
  size_t off = 0;
  auto alloc = [&](size_t bytes) -> void* {
    void* p = base + off;
    off += (bytes + 255) & ~(size_t)255;
    return p;
  };
  const size_t ND2 = (size_t)N_TOK * DMODEL * 2;
  unsigned short* Xbf = (unsigned short*)alloc(ND2);
  unsigned short* Qbf = (unsigned short*)alloc(ND2);
  unsigned short* Kbf = (unsigned short*)alloc(ND2);
  unsigned short* Vbf = (unsigned short*)alloc(ND2);
  unsigned short* Vt  = (unsigned short*)alloc(ND2);
  unsigned short* ATT = (unsigned short*)alloc(ND2);
  unsigned short* WT  = (unsigned short*)alloc((size_t)DMODEL * DMODEL * 2);
  float* mx = (float*)alloc((size_t)NHEAD * N_TOK * 4);
  float* rz = (float*)alloc((size_t)NHEAD * N_TOK * 4);
  float* Part = (float*)alloc((size_t)4 * NHEAD * N_TOK * 64 * 4);  // 32 MB
  size_t fixed = off;

  const size_t SZ = (size_t)N_TOK * N_TOK;
  int G = 16;
  // per-head: SB fp32 (16MB, reused for sim-bf16 + p-bf16) + P0 bf16 (8) + P0q fp8 (4) + PT fp8 (4)
  while (G > 1 && fixed + (size_t)G * SZ * 8 > ws_size) G >>= 1;
  float* SB           = (float*)alloc((size_t)G * SZ * 4);
  unsigned short* P0  = (unsigned short*)alloc((size_t)G * SZ * 2);
  unsigned char* P0q  = (unsigned char*)alloc((size_t)G * SZ);
  unsigned char* PT   = (unsigned char*)alloc((size_t)G * SZ);
  // aliases into SB (scores dead after softmax):
  unsigned short* SIMB = (unsigned short*)SB;              // bf16 sim, first half
  unsigned short* PB   = (unsigned short*)SB + G * SZ;     // bf16 p, second half

  auto gemm = [&](const GemmP& p, int nt, int mt, int batch) {
    gemm_bt_kernel<<<dim3(nt, mt, batch), 256, 0, stream>>>(p);
  };

  cast_f32_bf16_kernel<<<(N_TOK * DMODEL / 8) / 256, 256, 0, stream>>>(hs, Xbf);

  auto proj = [&](const float* W, const float* bias, unsigned short* dst) {
    transpose_w_kernel<<<dim3(32, 32), dim3(32, 8), 0, stream>>>(W, WT, DMODEL, DMODEL);
    GemmP p = {};
    p.A = Xbf; p.lda = DMODEL;
    p.B = WT;  p.ldb = DMODEL;
    p.bias = bias;
    p.Cb = dst; p.ldCb = DMODEL;
    p.M = N_TOK; p.N = DMODEL; p.K = DMODEL;
    p.alpha = 1.f;
    gemm(p, DMODEL / 128, N_TOK / 128, 1);
  };
  proj(Wq, bq, Qbf);
  proj(Wk, bk, Kbf);
  proj(Wv, bv, Vbf);
  transpose_bf_kernel<<<dim3(DMODEL / 32, N_TOK / 32), dim3(32, 8), 0, stream>>>(Vbf, Vt, N_TOK, DMODEL);

  const float sc_hd = 0.125f;
  const float sc_d  = 0.03125f;
  const float alpha = 0.05f;

  int ngroups = NHEAD / G;
  for (int gi = 0; gi < ngroups; gi++) {
    int h0 = gi * G;

    // scores = Q @ K^T (fp32 into SB)
    GemmP ps = {};
    ps.A = Qbf + h0 * HDIM; ps.sA = HDIM; ps.lda = DMODEL;
    ps.B = Kbf + h0 * HDIM; ps.sB = HDIM; ps.ldb = DMODEL;
    ps.Cf = SB; ps.sCf = (long long)SZ; ps.ldCf = N_TOK;
    ps.M = N_TOK; ps.N = N_TOK; ps.K = HDIM;
    ps.alpha = 1.f;
    gemm(ps, 16, 16, G);
    softmax_rows_kernel<<<G * N_TOK, 256, 0, stream>>>(SB, P0, P0q, sc_hd);

    // sim = K @ K^T (bf16 into SIMB, aliasing dead SB)
    GemmP pk = ps;
    pk.A = Kbf + h0 * HDIM;
    pk.Cf = nullptr;
    pk.Cb = SIMB; pk.sCb = (long long)SZ; pk.ldCb = N_TOK;
    gemm(pk, 16, 16, G);
    rowstats_bf_kernel<<<G * N_TOK, 256, 0, stream>>>(SIMB, mx, rz, sc_d);
    build_pt_kernel<<<dim3(N_TOK, G), 256, 0, stream>>>(SIMB, mx, rz, PT, sc_d);

    // p = 0.95*p0 + 0.05*(p0 @ P)  [fp8 GEMM, inputs scaled x256]
    Gemm8P g8 = {};
    g8.A = P0q; g8.sA = (long long)SZ; g8.lda = N_TOK;
    g8.B = PT;  g8.sB = (long long)SZ; g8.ldb = N_TOK;
    g8.Eb = P0; g8.sE = (long long)SZ; g8.ldE = N_TOK;
    g8.Cf = outp + (size_t)h0 * SZ; g8.sCf = (long long)SZ; g8.ldCf = N_TOK;
    g8.Cb = PB; g8.sCb = (long long)SZ; g8.ldCb = N_TOK;
    g8.K = N_TOK;
    g8.alpha = alpha * FP8_INV2;
    g8.beta = 1.f - alpha;
    gemm_fp8_kernel<<<dim3(16, 16, G), 256, 0, stream>>>(g8);

    // attn = p @ V  (K-split 4 + reduce)
    AttnP pa = {};
    pa.A = PB; pa.sA = (long long)SZ; pa.lda = N_TOK;
    pa.B = Vt + (size_t)h0 * HDIM * N_TOK; pa.sB = (long long)HDIM * N_TOK; pa.ldb = N_TOK;
    pa.Part = Part; pa.G = G;
    attn_part_kernel<<<dim3(16, G, 4), 256, 0, stream>>>(pa);
    attn_reduce_kernel<<<G * 128, 256, 0, stream>>>(Part, ATT, G, h0);
  }

  // out = attn @ Wo + bo
  transpose_w_kernel<<<dim3(32, 32), dim3(32, 8), 0, stream>>>(Wo, WT, DMODEL, DMODEL);
  GemmP po = {};
  po.A = ATT; po.lda = DMODEL;
  po.B = WT;  po.ldb = DMODEL;
  po.bias = bo;
  po.Cf = out; po.ldCf = DMODEL;
  po.M = N_TOK; po.N = DMODEL; po.K = DMODEL;
  po.alpha = 1.f;
  gemm(po, DMODEL / 128, N_TOK / 128, 1);
}

// Round 4
// 1204.538 us; speedup vs baseline: 1.1776x; 1.1776x over previous
//
#include <hip/hip_runtime.h>

#define N_TOK 2048
#define DMODEL 1024
#define NHEAD 16
#define HDIM 64

typedef __attribute__((ext_vector_type(8))) __bf16 bf16x8;
typedef __attribute__((ext_vector_type(4))) float f32x4;
typedef __attribute__((ext_vector_type(2))) long longx2;

__device__ __forceinline__ float bf2f(unsigned short h) {
  return __uint_as_float(((unsigned int)h) << 16);
}
__device__ __forceinline__ unsigned short f2bf(float f) {
  unsigned int u = __float_as_uint(f);
  unsigned int r = (u + 0x7fffu + ((u >> 16) & 1u)) >> 16;
  return (unsigned short)r;
}
// pack 4 floats -> 4 fp8 e4m3 (OCP on gfx950) bytes
__device__ __forceinline__ unsigned int pack4_fp8(float a, float b, float c, float d) {
  int v = __builtin_amdgcn_cvt_pk_fp8_f32(a, b, 0, false);
  v = __builtin_amdgcn_cvt_pk_fp8_f32(c, d, v, true);
  return (unsigned int)v;
}
// k-interleave for fp8 matrices: within each 64-byte k-block, 8B-chunk c and c+4
// become the lo/hi halves of 16B slot (c&3). k0 must be a multiple of 8.
__device__ __forceinline__ int k_remap8(int k0) {
  return (k0 & ~63) | (((k0 >> 3) & 3) << 4) | (((k0 >> 5) & 1) << 3);
}

__device__ __forceinline__ void async16(const void* g, void* l) {
  __builtin_amdgcn_global_load_lds((__attribute__((address_space(1))) void*)(g),
                                   (__attribute__((address_space(3))) void*)(l),
                                   16, 0, 0);
}

#define FP8_SCALE 256.0f
#define FP8_INV2  (1.0f / (256.0f * 256.0f))

// ---------------- bf16 GEMM: C = alpha*(A @ B^T) [+bias[col]] [+beta*Eb(bf16)] ----------------
struct GemmP {
  const unsigned short* A;
  const unsigned short* B;
  const unsigned short* Eb;
  const float* bias;
  float* Cf;
  unsigned short* Cb;
  long long sA, sB, sE, sCf, sCb;
  int lda, ldb, ldE, ldCf, ldCb;
  int M, N, K;
  float alpha, beta;
};

__global__ __launch_bounds__(256) void gemm_bt_kernel(GemmP g) {
  __shared__ __attribute__((aligned(16))) unsigned short As[128 * 32];
  __shared__ __attribute__((aligned(16))) unsigned short Bs[128 * 32];
  const int tid = threadIdx.x;
  const int lane = tid & 63;
  const int wv = tid >> 6;
  const int wr = wv >> 1, wc = wv & 1;
  const long long z = blockIdx.z;
  const unsigned short* A = g.A + z * g.sA;
  const unsigned short* B = g.B + z * g.sB;
  const int tm = blockIdx.y * 128;
  const int tn = blockIdx.x * 128;

  const int r0 = tid >> 2;
  const int r1 = (tid + 256) >> 2;
  const int kof = (tid & 3) * 8;
  int bn0 = tn + r0; if (bn0 > g.N - 1) bn0 = g.N - 1;
  int bn1 = tn + r1; if (bn1 > g.N - 1) bn1 = g.N - 1;

  const unsigned short* pa0 = A + (long long)(tm + r0) * g.lda + kof;
  const unsigned short* pa1 = A + (long long)(tm + r1) * g.lda + kof;
  const unsigned short* pb0 = B + (long long)bn0 * g.ldb + kof;
  const unsigned short* pb1 = B + (long long)bn1 * g.ldb + kof;

  unsigned short* la0 = &As[tid * 8];
  unsigned short* la1 = &As[(tid + 256) * 8];
  unsigned short* lb0 = &Bs[tid * 8];
  unsigned short* lb1 = &Bs[(tid + 256) * 8];

  const int aroff = (wr * 64 + (lane & 15)) * 32 + (lane >> 4) * 8;
  const int broff = (wc * 64 + (lane & 15)) * 32 + (lane >> 4) * 8;

  f32x4 acc[4][4] = {};

  for (int kk = 0; kk < g.K; kk += 32) {
    __syncthreads();
    async16(pa0 + kk, la0);
    async16(pa1 + kk, la1);
    async16(pb0 + kk, lb0);
    async16(pb1 + kk, lb1);
    __syncthreads();
    bf16x8 af[4], bfr[4];
#pragma unroll
    for (int i = 0; i < 4; i++)
      af[i] = *(const bf16x8*)&As[aroff + i * 16 * 32];
#pragma unroll
    for (int j = 0; j < 4; j++)
      bfr[j] = *(const bf16x8*)&Bs[broff + j * 16 * 32];
#pragma unroll
    for (int i = 0; i < 4; i++)
#pragma unroll
      for (int j = 0; j < 4; j++)
        acc[i][j] = __builtin_amdgcn_mfma_f32_16x16x32_bf16(af[i], bfr[j], acc[i][j], 0, 0, 0);
  }

  const unsigned short* Eb = g.Eb ? g.Eb + z * g.sE : nullptr;
  float* Cf = g.Cf ? g.Cf + z * g.sCf : nullptr;
  unsigned short* Cb = g.Cb ? g.Cb + z * g.sCb : nullptr;
  const int cbase = tn + wc * 64 + (lane & 15);
  const int rbase = tm + wr * 64 + (lane >> 4) * 4;
#pragma unroll
  for (int i = 0; i < 4; i++) {
#pragma unroll
    for (int j = 0; j < 4; j++) {
      int col = cbase + j * 16;
      if (col < g.N) {
        float bs = g.bias ? g.bias[col] : 0.f;
#pragma unroll
        for (int r = 0; r < 4; r++) {
          int row = rbase + i * 16 + r;
          float v = g.alpha * acc[i][j][r] + bs;
          if (Eb) v += g.beta * bf2f(Eb[(long long)row * g.ldE + col]);
          if (Cf) Cf[(long long)row * g.ldCf + col] = v;
          if (Cb) Cb[(long long)row * g.ldCb + col] = f2bf(v);
        }
      }
    }
  }
}

// ---------------- fp8 GEMM (diffusion): C = alpha*(A @ B^T) + beta*Eb ----------------
// A,B: [2048,K] fp8 row-major in k-interleaved layout (k_remap8). BK=64.
// One ds_read_b128 per fragment-pair: lo 8B = k in [8q,8q+8), hi = [32+8q,32+8q+8).
struct Gemm8P {
  const unsigned char* A;
  const unsigned char* B;
  const unsigned short* Eb;
  float* Cf;
  unsigned short* Cb;
  long long sA, sB, sE, sCf, sCb;
  int lda, ldb, ldE, ldCf, ldCb;
  int K;
  float alpha, beta;
};

__global__ __launch_bounds__(256) void gemm_fp8_kernel(Gemm8P g) {
  __shared__ __attribute__((aligned(16))) unsigned char As[128 * 64];
  __shared__ __attribute__((aligned(16))) unsigned char Bs[128 * 64];
  const int tid = threadIdx.x;
  const int lane = tid & 63;
  const int wv = tid >> 6;
  const int wr = wv >> 1, wc = wv & 1;
  const long long z = blockIdx.z;
  const unsigned char* A = g.A + z * g.sA;
  const unsigned char* B = g.B + z * g.sB;
  const int tm = blockIdx.y * 128;
  const int tn = blockIdx.x * 128;

  const int r0 = tid >> 2;
  const int r1 = 64 + (tid >> 2);
  const int kof = (tid & 3) * 16;
  const unsigned char* pa0 = A + (long long)(tm + r0) * g.lda + kof;
  const unsigned char* pa1 = A + (long long)(tm + r1) * g.lda + kof;
  const unsigned char* pb0 = B + (long long)(tn + r0) * g.ldb + kof;
  const unsigned char* pb1 = B + (long long)(tn + r1) * g.ldb + kof;
  unsigned char* la0 = &As[tid * 16];
  unsigned char* la1 = &As[(tid + 256) * 16];
  unsigned char* lb0 = &Bs[tid * 16];
  unsigned char* lb1 = &Bs[(tid + 256) * 16];

  // b128 read covering both k-sub-blocks (interleaved layout)
  const int aroff = (wr * 64 + (lane & 15)) * 64 + (lane >> 4) * 16;
  const int broff = (wc * 64 + (lane & 15)) * 64 + (lane >> 4) * 16;

  f32x4 acc[4][4] = {};

  for (int kk = 0; kk < g.K; kk += 64) {
    __syncthreads();
    async16(pa0 + kk, la0);
    async16(pa1 + kk, la1);
    async16(pb0 + kk, lb0);
    async16(pb1 + kk, lb1);
    __syncthreads();
    longx2 a2[4], b2[4];
#pragma unroll
    for (int i = 0; i < 4; i++)
      a2[i] = *(const longx2*)&As[aroff + i * 16 * 64];
#pragma unroll
    for (int j = 0; j < 4; j++)
      b2[j] = *(const longx2*)&Bs[broff + j * 16 * 64];
#pragma unroll
    for (int i = 0; i < 4; i++)
#pragma unroll
      for (int j = 0; j < 4; j++)
        acc[i][j] = __builtin_amdgcn_mfma_f32_16x16x32_fp8_fp8(a2[i].x, b2[j].x, acc[i][j], 0, 0, 0);
#pragma unroll
    for (int i = 0; i < 4; i++)
#pragma unroll
      for (int j = 0; j < 4; j++)
        acc[i][j] = __builtin_amdgcn_mfma_f32_16x16x32_fp8_fp8(a2[i].y, b2[j].y, acc[i][j], 0, 0, 0);
  }

  const unsigned short* Eb = g.Eb + z * g.sE;
  float* Cf = g.Cf + z * g.sCf;
  unsigned short* Cb = g.Cb + z * g.sCb;
  const int cbase = tn + wc * 64 + (lane & 15);
  const int rbase = tm + wr * 64 + (lane >> 4) * 4;
#pragma unroll
  for (int i = 0; i < 4; i++) {
#pragma unroll
    for (int j = 0; j < 4; j++) {
      int col = cbase + j * 16;
#pragma unroll
      for (int r = 0; r < 4; r++) {
        int row = rbase + i * 16 + r;
        float v = g.alpha * acc[i][j][r] + g.beta * bf2f(Eb[(long long)row * g.ldE + col]);
        Cf[(long long)row * g.ldCf + col] = v;
        Cb[(long long)row * g.ldCb + col] = f2bf(v);
      }
    }
  }
}

// ---------------- attn partial: Part = p(128-row tile) @ V (64 cols), K-split ----------------
struct AttnP {
  const unsigned short* A;  // p bf16 [N_TOK, N_TOK] per head
  const unsigned short* B;  // V^T bf16 [64, N_TOK] per head
  float* Part;              // [4][G][N_TOK][64]
  long long sA, sB;
  int lda, ldb, G;
};

__global__ __launch_bounds__(256) void attn_part_kernel(AttnP g) {
  __shared__ __attribute__((aligned(16))) unsigned short As[128 * 32];
  __shared__ __attribute__((aligned(16))) unsigned short Bs[64 * 32];
  const int tid = threadIdx.x;
  const int lane = tid & 63;
  const int w = tid >> 6;
  const int z = blockIdx.y;
  const int kz = blockIdx.z;
  const unsigned short* A = g.A + (long long)z * g.sA;
  const unsigned short* B = g.B + (long long)z * g.sB;
  const int tm = blockIdx.x * 128;
  const int k0 = kz * 512;

  const int rA0 = tid >> 2;
  const int rA1 = 64 + (tid >> 2);
  const int kof = (tid & 3) * 8;
  const unsigned short* pa0 = A + (long long)(tm + rA0) * g.lda + k0 + kof;
  const unsigned short* pa1 = A + (long long)(tm + rA1) * g.lda + k0 + kof;
  const unsigned short* pb0 = B + (long long)(tid >> 2) * g.ldb + k0 + kof;
  unsigned short* la0 = &As[tid * 8];
  unsigned short* la1 = &As[(tid + 256) * 8];
  unsigned short* lb0 = &Bs[tid * 8];

  const int aoff = (w * 32 + (lane & 15)) * 32 + (lane >> 4) * 8;
  const int boff = (lane & 15) * 32 + (lane >> 4) * 8;

  f32x4 acc[2][4] = {};

  for (int kk = 0; kk < 512; kk += 32) {
    __syncthreads();
    async16(pa0 + kk, la0);
    async16(pa1 + kk, la1);
    async16(pb0 + kk, lb0);
    __syncthreads();
    bf16x8 af[2], bfr[4];
#pragma unroll
    for (int i = 0; i < 2; i++)
      af[i] = *(const bf16x8*)&As[aoff + i * 16 * 32];
#pragma unroll
    for (int j = 0; j < 4; j++)
      bfr[j] = *(const bf16x8*)&Bs[boff + j * 16 * 32];
#pragma unroll
    for (int i = 0; i < 2; i++)
#pragma unroll
      for (int j = 0; j < 4; j++)
        acc[i][j] = __builtin_amdgcn_mfma_f32_16x16x32_bf16(af[i], bfr[j], acc[i][j], 0, 0, 0);
  }

  float* P = g.Part + ((long long)(kz * g.G + z) * N_TOK + tm) * 64;
#pragma unroll
  for (int i = 0; i < 2; i++) {
#pragma unroll
    for (int j = 0; j < 4; j++) {
      int col = (lane & 15) + j * 16;
#pragma unroll
      for (int r = 0; r < 4; r++) {
        int row = w * 32 + i * 16 + (lane >> 4) * 4 + r;
        P[(long long)row * 64 + col] = acc[i][j][r];
      }
    }
  }
}

// ATT[row][ (h0+z)*64 + col ] = bf16( sum_kz Part )
__global__ __launch_bounds__(256) void attn_reduce_kernel(const float* Part, unsigned short* ATT,
                                                          int G, int h0) {
  int idx = blockIdx.x * 256 + threadIdx.x;  // 4 floats each
  int f = idx * 4;
  int z = f / (N_TOK * 64);
  int rem = f % (N_TOK * 64);
  int row = rem >> 6;
  int col = rem & 63;
  long long stride = (long long)G * N_TOK * 64;
  const float* p0 = Part + ((long long)z * N_TOK + row) * 64 + col;
  float4 s = *(const float4*)p0;
  float4 a = *(const float4*)(p0 + stride);
  float4 b = *(const float4*)(p0 + 2 * stride);
  float4 c = *(const float4*)(p0 + 3 * stride);
  s.x += a.x + b.x + c.x; s.y += a.y + b.y + c.y;
  s.z += a.z + b.z + c.z; s.w += a.w + b.w + c.w;
  uint2 o;
  o.x = (unsigned)f2bf(s.x) | ((unsigned)f2bf(s.y) << 16);
  o.y = (unsigned)f2bf(s.z) | ((unsigned)f2bf(s.w) << 16);
  *(uint2*)&ATT[(long long)row * DMODEL + (h0 + z) * 64 + col] = o;
}

// ---------------- elementwise / transpose / softmax helpers ----------------

__global__ __launch_bounds__(256) void cast_f32_bf16_kernel(const float* x, unsigned short* y) {
  int i = blockIdx.x * 256 + threadIdx.x;
  const float4* src = (const float4*)x;
  float4 a = src[i * 2], b = src[i * 2 + 1];
  uint4 o;
  o.x = (unsigned)f2bf(a.x) | ((unsigned)f2bf(a.y) << 16);
  o.y = (unsigned)f2bf(a.z) | ((unsigned)f2bf(a.w) << 16);
  o.z = (unsigned)f2bf(b.x) | ((unsigned)f2bf(b.y) << 16);
  o.w = (unsigned)f2bf(b.z) | ((unsigned)f2bf(b.w) << 16);
  ((uint4*)y)[i] = o;
}

__global__ __launch_bounds__(256) void transpose_w_kernel(const float* in, unsigned short* out,
                                                          int rows, int cols) {
  __shared__ float t[32][33];
  int c = blockIdx.x * 32 + threadIdx.x;
  int r0 = blockIdx.y * 32;
#pragma unroll
  for (int j = 0; j < 32; j += 8)
    t[threadIdx.y + j][threadIdx.x] = in[(long long)(r0 + threadIdx.y + j) * cols + c];
  __syncthreads();
  int r = r0 + threadIdx.x;
#pragma unroll
  for (int j = 0; j < 32; j += 8)
    out[(long long)(blockIdx.x * 32 + threadIdx.y + j) * rows + r] =
        f2bf(t[threadIdx.x][threadIdx.y + j]);
}

__global__ __launch_bounds__(256) void transpose_bf_kernel(const unsigned short* in,
                                                           unsigned short* out,
                                                           int rows, int cols) {
  __shared__ unsigned short t[32][34];
  int c = blockIdx.x * 32 + threadIdx.x;
  int r0 = blockIdx.y * 32;
#pragma unroll
  for (int j = 0; j < 32; j += 8)
    t[threadIdx.y + j][threadIdx.x] = in[(long long)(r0 + threadIdx.y + j) * cols + c];
  __syncthreads();
  int r = r0 + threadIdx.x;
#pragma unroll
  for (int j = 0; j < 32; j += 8)
    out[(long long)(blockIdx.x * 32 + threadIdx.y + j) * rows + r] = t[threadIdx.x][threadIdx.y + j];
}

// softmax over fp32 rows -> bf16 P0 and fp8 P0q (scaled by FP8_SCALE, k-interleaved)
__global__ __launch_bounds__(256) void softmax_rows_kernel(const float* S, unsigned short* P,
                                                           unsigned char* P8, float scale) {
  __shared__ float redm[4];
  __shared__ float reds[4];
  long long row = blockIdx.x;
  const float4* src = (const float4*)(S + row * 2048);
  float4 A = src[threadIdx.x * 2], B = src[threadIdx.x * 2 + 1];
  float v[8] = {A.x, A.y, A.z, A.w, B.x, B.y, B.z, B.w};
#pragma unroll
  for (int i = 0; i < 8; i++) v[i] *= scale;
  float m = v[0];
#pragma unroll
  for (int i = 1; i < 8; i++) m = fmaxf(m, v[i]);
#pragma unroll
  for (int o = 32; o > 0; o >>= 1) m = fmaxf(m, __shfl_xor(m, o));
  if ((threadIdx.x & 63) == 0) redm[threadIdx.x >> 6] = m;
  __syncthreads();
  m = fmaxf(fmaxf(redm[0], redm[1]), fmaxf(redm[2], redm[3]));
  float e[8];
  float s = 0.f;
#pragma unroll
  for (int i = 0; i < 8; i++) { e[i] = __expf(v[i] - m); s += e[i]; }
#pragma unroll
  for (int o = 32; o > 0; o >>= 1) s += __shfl_xor(s, o);
  if ((threadIdx.x & 63) == 0) reds[threadIdx.x >> 6] = s;
  __syncthreads();
  s = (reds[0] + reds[1]) + (reds[2] + reds[3]);
  float inv = 1.f / s;
  float p[8];
#pragma unroll
  for (int i = 0; i < 8; i++) p[i] = e[i] * inv;
  uint4 o4;
  o4.x = (unsigned)f2bf(p[0]) | ((unsigned)f2bf(p[1]) << 16);
  o4.y = (unsigned)f2bf(p[2]) | ((unsigned)f2bf(p[3]) << 16);
  o4.z = (unsigned)f2bf(p[4]) | ((unsigned)f2bf(p[5]) << 16);
  o4.w = (unsigned)f2bf(p[6]) | ((unsigned)f2bf(p[7]) << 16);
  ((uint4*)(P + row * 2048))[threadIdx.x] = o4;
  uint2 q;
  q.x = pack4_fp8(p[0] * FP8_SCALE, p[1] * FP8_SCALE, p[2] * FP8_SCALE, p[3] * FP8_SCALE);
  q.y = pack4_fp8(p[4] * FP8_SCALE, p[5] * FP8_SCALE, p[6] * FP8_SCALE, p[7] * FP8_SCALE);
  *(uint2*)(P8 + row * 2048 + k_remap8(threadIdx.x * 8)) = q;
}

// per-row max and 1/sumexp from bf16 sim
__global__ __launch_bounds__(256) void rowstats_bf_kernel(const unsigned short* S, float* mx,
                                                          float* rz, float scale) {
  __shared__ float redm[4];
  __shared__ float reds[4];
  long long row = blockIdx.x;
  uint4 raw = ((const uint4*)(S + row * 2048))[threadIdx.x];
  unsigned int w[4] = {raw.x, raw.y, raw.z, raw.w};
  float v[8];
#pragma unroll
  for (int i = 0; i < 4; i++) {
    v[2 * i] = bf2f((unsigned short)(w[i] & 0xffff)) * scale;
    v[2 * i + 1] = bf2f((unsigned short)(w[i] >> 16)) * scale;
  }
  float m = v[0];
#pragma unroll
  for (int i = 1; i < 8; i++) m = fmaxf(m, v[i]);
#pragma unroll
  for (int o = 32; o > 0; o >>= 1) m = fmaxf(m, __shfl_xor(m, o));
  if ((threadIdx.x & 63) == 0) redm[threadIdx.x >> 6] = m;
  __syncthreads();
  m = fmaxf(fmaxf(redm[0], redm[1]), fmaxf(redm[2], redm[3]));
  float s = 0.f;
#pragma unroll
  for (int i = 0; i < 8; i++) s += __expf(v[i] - m);
#pragma unroll
  for (int o = 32; o > 0; o >>= 1) s += __shfl_xor(s, o);
  if ((threadIdx.x & 63) == 0) reds[threadIdx.x >> 6] = s;
  __syncthreads();
  if (threadIdx.x == 0) {
    s = (reds[0] + reds[1]) + (reds[2] + reds[3]);
    mx[row] = m;
    rz[row] = 1.f / s;
  }
}

// PT(fp8, xFP8_SCALE, k-interleaved)[z][m][n] = exp(scale*S[z][m][n]-mx[n])*rz[n]  (sim symmetric)
__global__ __launch_bounds__(256) void build_pt_kernel(const unsigned short* S, const float* mx,
                                                       const float* rz, unsigned char* PT,
                                                       float scale) {
  long long z = blockIdx.y;
  long long m = blockIdx.x;
  uint4 raw = ((const uint4*)(S + (z * 2048 + m) * 2048))[threadIdx.x];
  unsigned int w[4] = {raw.x, raw.y, raw.z, raw.w};
  float v[8];
#pragma unroll
  for (int i = 0; i < 4; i++) {
    v[2 * i] = bf2f((unsigned short)(w[i] & 0xffff)) * scale;
    v[2 * i + 1] = bf2f((unsigned short)(w[i] >> 16)) * scale;
  }
  const float4* mx4 = (const float4*)(mx + z * 2048);
  const float4* rz4 = (const float4*)(rz + z * 2048);
  float4 ma = mx4[threadIdx.x * 2], mb = mx4[threadIdx.x * 2 + 1];
  float4 ra = rz4[threadIdx.x * 2], rb = rz4[threadIdx.x * 2 + 1];
  float p[8];
  p[0] = __expf(v[0] - ma.x) * ra.x * FP8_SCALE;
  p[1] = __expf(v[1] - ma.y) * ra.y * FP8_SCALE;
  p[2] = __expf(v[2] - ma.z) * ra.z * FP8_SCALE;
  p[3] = __expf(v[3] - ma.w) * ra.w * FP8_SCALE;
  p[4] = __expf(v[4] - mb.x) * rb.x * FP8_SCALE;
  p[5] = __expf(v[5] - mb.y) * rb.y * FP8_SCALE;
  p[6] = __expf(v[6] - mb.z) * rb.z * FP8_SCALE;
  p[7] = __expf(v[7] - mb.w) * rb.w * FP8_SCALE;
  uint2 q;
  q.x = pack4_fp8(p[0], p[1], p[2], p[3]);
  q.y = pack4_fp8(p[4], p[5], p[6], p[7]);
  *(uint2*)(PT + (z * 2048 + m) * 2048 + k_remap8(threadIdx.x * 8)) = q;
}

// ---------------- driver ----------------

extern "C" void kernel_launch(void* const* d_in, const int* in_sizes, int n_in,
                              void* d_out, int out_size, void* d_ws, size_t ws_size,
                              hipStream_t stream) {
  const float* hs = (const float*)d_in[0];
  const float* Wq = (const float*)d_in[1];
  const float* bq = (const float*)d_in[2];
  const float* Wk = (const float*)d_in[3];
  const float* bk = (const float*)d_in[4];
  const float* Wv = (const float*)d_in[5];
  const float* bv = (const float*)d_in[6];
  const float* Wo = (const float*)d_in[7];
  const float* bo = (const float*)d_in[8];
  float* out = (float*)d_out;
  float* outp = out + (size_t)N_TOK * DMODEL;

  char* base = (char*)d_ws;
  size_t off = 0;
  auto alloc = [&](size_t bytes) -> void* {
    void* p = base + off;
    off += (bytes + 255) & ~(size_t)255;
    return p;
  };
  const size_t ND2 = (size_t)N_TOK * DMODEL * 2;
  unsigned short* Xbf = (unsigned short*)alloc(ND2);
  unsigned short* Qbf = (unsigned short*)alloc(ND2);
  unsigned short* Kbf = (unsigned short*)alloc(ND2);
  unsigned short* Vbf = (unsigned short*)alloc(ND2);
  unsigned short* Vt  = (unsigned short*)alloc(ND2);
  unsigned short* ATT = (unsigned short*)alloc(ND2);
  unsigned short* WT  = (unsigned short*)alloc((size_t)DMODEL * DMODEL * 2);
  float* mx = (float*)alloc((size_t)NHEAD * N_TOK * 4);
  float* rz = (float*)alloc((size_t)NHEAD * N_TOK * 4);
  float* Part = (float*)alloc((size_t)4 * NHEAD * N_TOK * 64 * 4);  // 32 MB
  size_t fixed = off;

  const size_t SZ = (size_t)N_TOK * N_TOK;
  int G = 16;
  while (G > 1 && fixed + (size_t)G * SZ * 8 > ws_size) G >>= 1;
  float* SB           = (float*)alloc((size_t)G * SZ * 4);
  unsigned short* P0  = (unsigned short*)alloc((size_t)G * SZ * 2);
  unsigned char* P0q  = (unsigned char*)alloc((size_t)G * SZ);
  unsigned char* PT   = (unsigned char*)alloc((size_t)G * SZ);
  // aliases into SB (scores dead after softmax):
  unsigned short* SIMB = (unsigned short*)SB;              // bf16 sim, first half
  unsigned short* PB   = (unsigned short*)SB + G * SZ;     // bf16 p, second half

  auto gemm = [&](const GemmP& p, int nt, int mt, int batch) {
    gemm_bt_kernel<<<dim3(nt, mt, batch), 256, 0, stream>>>(p);
  };

  cast_f32_bf16_kernel<<<(N_TOK * DMODEL / 8) / 256, 256, 0, stream>>>(hs, Xbf);

  auto proj = [&](const float* W, const float* bias, unsigned short* dst) {
    transpose_w_kernel<<<dim3(32, 32), dim3(32, 8), 0, stream>>>(W, WT, DMODEL, DMODEL);
    GemmP p = {};
    p.A = Xbf; p.lda = DMODEL;
    p.B = WT;  p.ldb = DMODEL;
    p.bias = bias;
    p.Cb = dst; p.ldCb = DMODEL;
    p.M = N_TOK; p.N = DMODEL; p.K = DMODEL;
    p.alpha = 1.f;
    gemm(p, DMODEL / 128, N_TOK / 128, 1);
  };
  proj(Wq, bq, Qbf);
  proj(Wk, bk, Kbf);
  proj(Wv, bv, Vbf);
  transpose_bf_kernel<<<dim3(DMODEL / 32, N_TOK / 32), dim3(32, 8), 0, stream>>>(Vbf, Vt, N_TOK, DMODEL);

  const float sc_hd = 0.125f;
  const float sc_d  = 0.03125f;
  const float alpha = 0.05f;

  int ngroups = NHEAD / G;
  for (int gi = 0; gi < ngroups; gi++) {
    int h0 = gi * G;

    // scores = Q @ K^T (fp32 into SB)
    GemmP ps = {};
    ps.A = Qbf + h0 * HDIM; ps.sA = HDIM; ps.lda = DMODEL;
    ps.B = Kbf + h0 * HDIM; ps.sB = HDIM; ps.ldb = DMODEL;
    ps.Cf = SB; ps.sCf = (long long)SZ; ps.ldCf = N_TOK;
    ps.M = N_TOK; ps.N = N_TOK; ps.K = HDIM;
    ps.alpha = 1.f;
    gemm(ps, 16, 16, G);
    softmax_rows_kernel<<<G * N_TOK, 256, 0, stream>>>(SB, P0, P0q, sc_hd);

    // sim = K @ K^T (bf16 into SIMB, aliasing dead SB)
    GemmP pk = ps;
    pk.A = Kbf + h0 * HDIM;
    pk.Cf = nullptr;
    pk.Cb = SIMB; pk.sCb = (long long)SZ; pk.ldCb = N_TOK;
    gemm(pk, 16, 16, G);
    rowstats_bf_kernel<<<G * N_TOK, 256, 0, stream>>>(SIMB, mx, rz, sc_d);
    build_pt_kernel<<<dim3(N_TOK, G), 256, 0, stream>>>(SIMB, mx, rz, PT, sc_d);

    // p = 0.95*p0 + 0.05*(p0 @ P)  [fp8 GEMM, inputs scaled x256, k-interleaved]
    Gemm8P g8 = {};
    g8.A = P0q; g8.sA = (long long)SZ; g8.lda = N_TOK;
    g8.B = PT;  g8.sB = (long long)SZ; g8.ldb = N_TOK;
    g8.Eb = P0; g8.sE = (long long)SZ; g8.ldE = N_TOK;
    g8.Cf = outp + (size_t)h0 * SZ; g8.sCf = (long long)SZ; g8.ldCf = N_TOK;
    g8.Cb = PB; g8.sCb = (long long)SZ; g8.ldCb = N_TOK;
    g8.K = N_TOK;
    g8.alpha = alpha * FP8_INV2;
    g8.beta = 1.f - alpha;
    gemm_fp8_kernel<<<dim3(16, 16, G), 256, 0, stream>>>(g8);

    // attn = p @ V  (K-split 4 + reduce)
    AttnP pa = {};
    pa.A = PB; pa.sA = (long long)SZ; pa.lda = N_TOK;
    pa.B = Vt + (size_t)h0 * HDIM * N_TOK; pa.sB = (long long)HDIM * N_TOK; pa.ldb = N_TOK;
    pa.Part = Part; pa.G = G;
    attn_part_kernel<<<dim3(16, G, 4), 256, 0, stream>>>(pa);
    attn_reduce_kernel<<<G * 128, 256, 0, stream>>>(Part, ATT, G, h0);
  }

  // out = attn @ Wo + bo
  transpose_w_kernel<<<dim3(32, 32), dim3(32, 8), 0, stream>>>(Wo, WT, DMODEL, DMODEL);
  GemmP po = {};
  po.A = ATT; po.lda = DMODEL;
  po.B = WT;  po.ldb = DMODEL;
  po.bias = bo;
  po.Cf = out; po.ldCf = DMODEL;
  po.M = N_TOK; po.N = DMODEL; po.K = DMODEL;
  po.alpha = 1.f;
  gemm(po, DMODEL / 128, N_TOK / 128, 1);
}